// Round 3
// baseline (35.729 us; speedup 1.0000x reference)
//
#include <hip/hip_runtime.h>

// AttnCutLoss: loss = -(1/B) * sum_b [ (sum_s log(output[b,s])) / (sum_s exp(r_bs/TAU)) ]
// r_bs = 2*tp_bs / (k + total_b)   (F1, algebraically simplified; exact for the
// reference's tp=0 / total=0 where() branches).  B = S = 4096, TAU = 0.95, fp32.
//
// One 64-lane wave per row: no barriers, no LDS. Cross-lane label prefix via
// ballot + mbcnt (labels are exactly 0/1); chunk prefixes ride the scalar pipe.

#define SROW 4096
#define NROWS 4096
#define NCHUNK 16           // SROW / (64 lanes * 4 floats)

__global__ __launch_bounds__(64, 4) void attncut_row_kernel(
    const float* __restrict__ output,   // [B,S,1]
    const float* __restrict__ labels,   // [B,S]
    float* __restrict__ row_out)        // [B] : L_b / norm_b
{
    const int b    = blockIdx.x;
    const int lane = threadIdx.x;       // 0..63

    const float4* lab4 = reinterpret_cast<const float4*>(labels) + (size_t)b * (SROW / 4) + lane;
    const float4* out4 = reinterpret_cast<const float4*>(output) + (size_t)b * (SROW / 4) + lane;

    // ---- issue all label loads (each instr = contiguous 1 KB, fully coalesced) ----
    float4 L[NCHUNK];
    #pragma unroll
    for (int c = 0; c < NCHUNK; ++c) L[c] = lab4[c * 64];

    // ---- issue first half of output loads early (latency overlaps the scan) ----
    float4 O0[8];
    #pragma unroll
    for (int c = 0; c < 8; ++c) O0[c] = out4[c * 64];

    // ---- prefix counts: ballot + mbcnt (exact integer counts, no shuffles) ----
    float T[NCHUNK][4];      // inclusive tp within chunk (below-lane + local prefix)
    float P[NCHUNK];         // exclusive chunk prefix (wave-uniform, SGPR)
    unsigned int run = 0;    // running label count (scalar pipe)
    #pragma unroll
    for (int c = 0; c < NCHUNK; ++c) {
        unsigned long long b0 = __ballot(L[c].x > 0.5f);
        unsigned long long b1 = __ballot(L[c].y > 0.5f);
        unsigned long long b2 = __ballot(L[c].z > 0.5f);
        unsigned long long b3 = __ballot(L[c].w > 0.5f);
        unsigned int acc = __builtin_amdgcn_mbcnt_lo((unsigned int)b0, 0u);
        acc = __builtin_amdgcn_mbcnt_hi((unsigned int)(b0 >> 32), acc);
        acc = __builtin_amdgcn_mbcnt_lo((unsigned int)b1, acc);
        acc = __builtin_amdgcn_mbcnt_hi((unsigned int)(b1 >> 32), acc);
        acc = __builtin_amdgcn_mbcnt_lo((unsigned int)b2, acc);
        acc = __builtin_amdgcn_mbcnt_hi((unsigned int)(b2 >> 32), acc);
        acc = __builtin_amdgcn_mbcnt_lo((unsigned int)b3, acc);
        acc = __builtin_amdgcn_mbcnt_hi((unsigned int)(b3 >> 32), acc);
        float below = (float)acc;
        float p0 = L[c].x;
        float p1 = p0 + L[c].y;
        float p2 = p1 + L[c].z;
        float p3 = p2 + L[c].w;
        T[c][0] = below + p0;
        T[c][1] = below + p1;
        T[c][2] = below + p2;
        T[c][3] = below + p3;
        P[c] = (float)run;
        run += (unsigned int)(__popcll(b0) + __popcll(b1) + __popcll(b2) + __popcll(b3));
    }
    const float total = (float)run;

    // ---- lsum over first output batch ----
    float lsum = 0.f;
    #pragma unroll
    for (int c = 0; c < 8; ++c)
        lsum += __logf(O0[c].x) + __logf(O0[c].y) + __logf(O0[c].z) + __logf(O0[c].w);

    // ---- issue second output batch; its latency hides under qsum's trans work ----
    float4 O1[8];
    #pragma unroll
    for (int c = 0; c < 8; ++c) O1[c] = out4[(c + 8) * 64];

    // ---- qsum = sum exp(2*tp / (TAU*(k+total))) ----
    const float cst   = 2.0f / 0.95f;
    const float kbase = (float)(lane * 4 + 1) + total;
    float qsum = 0.f;
    #pragma unroll
    for (int c = 0; c < NCHUNK; ++c) {
        #pragma unroll
        for (int j = 0; j < 4; ++j) {
            float tp = P[c] + T[c][j];
            float kf = kbase + (float)(c * 256 + j);
            qsum += __expf(cst * tp * __builtin_amdgcn_rcpf(kf));
        }
    }

    // ---- lsum over second output batch ----
    #pragma unroll
    for (int c = 0; c < 8; ++c)
        lsum += __logf(O1[c].x) + __logf(O1[c].y) + __logf(O1[c].z) + __logf(O1[c].w);

    // ---- wave reduction, lane 0 writes ----
    #pragma unroll
    for (int d = 32; d > 0; d >>= 1) {
        qsum += __shfl_down(qsum, d, 64);
        lsum += __shfl_down(lsum, d, 64);
    }
    if (lane == 0) row_out[b] = lsum / qsum;
}

__global__ __launch_bounds__(1024) void attncut_final_kernel(
    const float* __restrict__ row_out, float* __restrict__ d_out)
{
    const int tid = threadIdx.x;
    float s = 0.f;
    for (int i = tid; i < NROWS; i += 1024) s += row_out[i];
    #pragma unroll
    for (int d = 32; d > 0; d >>= 1) s += __shfl_down(s, d, 64);
    __shared__ float sm[16];
    const int lane = tid & 63, wave = tid >> 6;
    if (lane == 0) sm[wave] = s;
    __syncthreads();
    if (tid == 0) {
        float t = 0.f;
        #pragma unroll
        for (int w = 0; w < 16; ++w) t += sm[w];
        d_out[0] = -t / (float)NROWS;
    }
}

extern "C" void kernel_launch(void* const* d_in, const int* in_sizes, int n_in,
                              void* d_out, int out_size, void* d_ws, size_t ws_size,
                              hipStream_t stream) {
    const float* output = (const float*)d_in[0];   // [B,S,1] fp32
    const float* labels = (const float*)d_in[1];   // [B,S]   fp32
    float* out  = (float*)d_out;
    float* rows = (float*)d_ws;                    // NROWS floats of scratch

    attncut_row_kernel<<<NROWS, 64, 0, stream>>>(output, labels, rows);
    attncut_final_kernel<<<1, 1024, 0, stream>>>(rows, out);
}

// Round 4
// 29.163 us; speedup vs baseline: 1.2251x; 1.2251x over previous
//
#include <hip/hip_runtime.h>

// AttnCutLoss: loss = -(1/B) * sum_b [ (sum_s log(output[b,s])) / (sum_s exp(r_bs/TAU)) ]
// r_bs = 2*tp_bs / (k + total_b)   (F1, algebraically simplified; exact for the
// reference's tp=0 / total=0 where() branches).  B = S = 4096, TAU = 0.95, fp32.
//
// 2 rows per 256-thread block, software-pipelined: next row's label loads and the
// current row's output loads are in flight across the scan's barriers.

#define BDIM 256
#define VPT 16              // values per thread; BDIM*VPT == SROW
#define ROWSPB 2
#define SROW 4096
#define NROWS 4096

__global__ __launch_bounds__(BDIM, 6) void attncut_row_kernel(
    const float* __restrict__ output,   // [B,S,1]
    const float* __restrict__ labels,   // [B,S]
    float* __restrict__ row_out)        // [B] : L_b / norm_b
{
    const int tid  = threadIdx.x;       // 0..255
    const int lane = tid & 63;
    const int wave = tid >> 6;          // 0..3
    const int base = tid * VPT;
    const int r0   = blockIdx.x * ROWSPB;

    const float4* lab4 = reinterpret_cast<const float4*>(labels + (size_t)r0 * SROW + base);
    const float4* out4 = reinterpret_cast<const float4*>(output + (size_t)r0 * SROW + base);
    const int ROWSTRIDE = SROW / 4;     // in float4 units

    __shared__ float wtot[4], wpre[4], s_total;
    __shared__ float sq[4], sl[4];

    // Prologue: row r0's labels.
    float4 Lc[4];
    #pragma unroll
    for (int i = 0; i < 4; ++i) Lc[i] = lab4[i];

    #pragma unroll
    for (int r = 0; r < ROWSPB; ++r) {
        // Prefetch next row's labels — in flight across this row's entire pipeline.
        float4 Ln[4];
        if (r + 1 < ROWSPB) {
            #pragma unroll
            for (int i = 0; i < 4; ++i) Ln[i] = lab4[(r + 1) * ROWSTRIDE + i];
        }

        // Thread-local inclusive prefix of labels (exact: labels are 0.0/1.0).
        float pre[VPT];
        {
            float v[VPT];
            #pragma unroll
            for (int i = 0; i < 4; ++i) {
                v[4*i+0] = Lc[i].x; v[4*i+1] = Lc[i].y; v[4*i+2] = Lc[i].z; v[4*i+3] = Lc[i].w;
            }
            float acc = 0.f;
            #pragma unroll
            for (int i = 0; i < VPT; ++i) { acc += v[i]; pre[i] = acc; }
        }
        const float cnt = pre[VPT - 1];

        // Issue this row's output loads now: latency hides under scan + barriers + qsum.
        float4 Ov[4];
        #pragma unroll
        for (int i = 0; i < 4; ++i) Ov[i] = out4[r * ROWSTRIDE + i];

        // Wave-level inclusive scan of per-thread counts.
        float sc = cnt;
        #pragma unroll
        for (int d = 1; d < 64; d <<= 1) {
            float n = __shfl_up(sc, d, 64);
            if (lane >= d) sc += n;
        }

        if (lane == 63) wtot[wave] = sc;
        __syncthreads();
        if (tid == 0) {
            float a = 0.f;
            #pragma unroll
            for (int w = 0; w < 4; ++w) { wpre[w] = a; a += wtot[w]; }
            s_total = a;
        }
        __syncthreads();
        const float total = s_total;
        const float excl  = wpre[wave] + (sc - cnt);

        // qsum = sum exp(2*tp / (TAU*(k+total))), fast rcp for the divide.
        const float c = 2.0f / 0.95f;
        float qsum = 0.f;
        #pragma unroll
        for (int i = 0; i < VPT; ++i) {
            float tp = excl + pre[i];
            float kf = (float)(base + i + 1) + total;
            qsum += __expf(c * tp * __builtin_amdgcn_rcpf(kf));
        }

        // lsum over this row's outputs (loads issued pre-barrier, arrived by now).
        float lsum = 0.f;
        #pragma unroll
        for (int i = 0; i < 4; ++i)
            lsum += __logf(Ov[i].x) + __logf(Ov[i].y) + __logf(Ov[i].z) + __logf(Ov[i].w);

        // Block reduction of (qsum, lsum).
        #pragma unroll
        for (int d = 32; d > 0; d >>= 1) {
            qsum += __shfl_down(qsum, d, 64);
            lsum += __shfl_down(lsum, d, 64);
        }
        if (lane == 0) { sq[wave] = qsum; sl[wave] = lsum; }
        __syncthreads();
        if (tid == 0) {
            float Q = 0.f, L = 0.f;
            #pragma unroll
            for (int w = 0; w < 4; ++w) { Q += sq[w]; L += sl[w]; }
            row_out[r0 + r] = L / Q;
        }

        // Rotate pipeline.
        if (r + 1 < ROWSPB) {
            #pragma unroll
            for (int i = 0; i < 4; ++i) Lc[i] = Ln[i];
        }
    }
}

__global__ __launch_bounds__(1024) void attncut_final_kernel(
    const float* __restrict__ row_out, float* __restrict__ d_out)
{
    const int tid = threadIdx.x;
    float s = 0.f;
    for (int i = tid; i < NROWS; i += 1024) s += row_out[i];
    #pragma unroll
    for (int d = 32; d > 0; d >>= 1) s += __shfl_down(s, d, 64);
    __shared__ float sm[16];
    const int lane = tid & 63, wave = tid >> 6;
    if (lane == 0) sm[wave] = s;
    __syncthreads();
    if (tid == 0) {
        float t = 0.f;
        #pragma unroll
        for (int w = 0; w < 16; ++w) t += sm[w];
        d_out[0] = -t / (float)NROWS;
    }
}

extern "C" void kernel_launch(void* const* d_in, const int* in_sizes, int n_in,
                              void* d_out, int out_size, void* d_ws, size_t ws_size,
                              hipStream_t stream) {
    const float* output = (const float*)d_in[0];   // [B,S,1] fp32
    const float* labels = (const float*)d_in[1];   // [B,S]   fp32
    float* out  = (float*)d_out;
    float* rows = (float*)d_ws;                    // NROWS floats of scratch

    attncut_row_kernel<<<NROWS / ROWSPB, BDIM, 0, stream>>>(output, labels, rows);
    attncut_final_kernel<<<1, 1024, 0, stream>>>(rows, out);
}